// Round 4
// baseline (491.968 us; speedup 1.0000x reference)
//
#include <hip/hip_runtime.h>
#include <hip/hip_bf16.h>
#include <stdint.h>

// Problem constants
#define S2   2048
#define DD   4096
#define NH   32
#define NKVH 8
#define HD2  128
// qkv buffer row width: 4096 (q) + 1024 (k) + 1024 (v)
#define QKVW 6144

typedef __bf16 bf16x8 __attribute__((ext_vector_type(8)));
typedef float  f32x4  __attribute__((ext_vector_type(4)));
typedef unsigned short u16x8 __attribute__((ext_vector_type(8)));
typedef unsigned short u16x4 __attribute__((ext_vector_type(4)));

__device__ __forceinline__ unsigned short f2b(float f) {
    unsigned int u = __builtin_bit_cast(unsigned int, f);
    unsigned int r = (u + 0x7FFFu + ((u >> 16) & 1u)) >> 16;   // RNE
    return (unsigned short)r;
}
__device__ __forceinline__ float b2f(unsigned short h) {
    unsigned int u = ((unsigned int)h) << 16;
    return __builtin_bit_cast(float, u);
}

// global -> LDS direct copy, 16B per lane. LDS dest is wave-uniform base + lane*16.
__device__ __forceinline__ void gload_lds16(const void* g, void* lds) {
    __builtin_amdgcn_global_load_lds(
        (const __attribute__((address_space(1))) void*)(uintptr_t)g,
        (__attribute__((address_space(3))) void*)(uint32_t)(uintptr_t)lds,
        16, 0, 0);
}

// raw barrier (no vmcnt drain) + compiler memory fences so LDS ops don't cross
#define BAR() do { asm volatile("" ::: "memory"); \
                   __builtin_amdgcn_s_barrier();  \
                   asm volatile("" ::: "memory"); } while (0)
#define WAITV(n) asm volatile("s_waitcnt vmcnt(" #n ")" ::: "memory")

// ---------------------------------------------------------------------------
// 1) fp32 -> bf16 conversion for x, wq, wk, wv, wo (concatenated into ws)
// ---------------------------------------------------------------------------
__global__ void cvt_all(const float* __restrict__ x,  const float* __restrict__ wq,
                        const float* __restrict__ wk, const float* __restrict__ wv,
                        const float* __restrict__ wo, unsigned short* __restrict__ dst) {
    const long long NG = 12LL * 1024 * 1024;  // float4 groups
    const long long stride = (long long)gridDim.x * blockDim.x;
    for (long long g = (long long)blockIdx.x * blockDim.x + threadIdx.x; g < NG; g += stride) {
        const float* src; long long off;
        if      (g < 2LL*1024*1024) { src = x;  off = g; }
        else if (g < 6LL*1024*1024) { src = wq; off = g - 2LL*1024*1024; }
        else if (g < 7LL*1024*1024) { src = wk; off = g - 6LL*1024*1024; }
        else if (g < 8LL*1024*1024) { src = wv; off = g - 7LL*1024*1024; }
        else                        { src = wo; off = g - 8LL*1024*1024; }
        f32x4 v = *reinterpret_cast<const f32x4*>(src + off * 4);
        u16x4 o;
        o[0] = f2b(v[0]); o[1] = f2b(v[1]); o[2] = f2b(v[2]); o[3] = f2b(v[3]);
        *reinterpret_cast<u16x4*>(dst + g * 4) = o;
    }
}

// ---------------------------------------------------------------------------
// 2) GEMM  C[M x N] = A[M x K] * B^T, 256x256 tile, BK=64, 8-phase schedule
//    (T2 st-swizzle + T3/T4 counted vmcnt + T5 setprio). Unchanged from r3.
// ---------------------------------------------------------------------------
template<typename CT>
__global__ __launch_bounds__(512) void gemm256(
    const unsigned short* __restrict__ A,
    const unsigned short* __restrict__ B0,
    const unsigned short* __restrict__ B1,
    const unsigned short* __restrict__ B2,
    int nb0, int nb01,
    CT* __restrict__ C, int ldc)
{
    constexpr int K = 4096, BK = 64, NT = K / BK;
    __shared__ unsigned short As[2][256 * 64];
    __shared__ unsigned short Bs[2][256 * 64];

    const int bm = blockIdx.y, bn = blockIdx.x;
    const int tid = threadIdx.x;
    const int w = tid >> 6, lane = tid & 63;
    const int wr = w >> 2, wc = w & 3;          // 2M x 4N wave grid
    const int r16 = lane & 15, g4 = lane >> 4;

    const int bn0 = bn * 256;
    const unsigned short* Bp;
    if      (bn0 < nb0)  Bp = B0 + (size_t)bn0 * K;
    else if (bn0 < nb01) Bp = B1 + (size_t)(bn0 - nb0) * K;
    else                 Bp = B2 + (size_t)(bn0 - nb01) * K;
    const unsigned short* Ap = A + (size_t)bm * 256 * K;

    const int lrow = lane >> 3;   // 0..7
    const int lchk = lane & 7;    // 0..7

    f32x4 acc[8][4] = {};
    bf16x8 af[4][2], b0[2][2], b1[2][2];

    auto stageA = [&](int buf, int tt, int half) {
        #pragma unroll
        for (int i = 0; i < 2; ++i) {
            const int s  = i * 8 + w;                                  // 0..15
            const int rb = ((s & 7) * 8) + ((s >> 3) * 128) + half * 64;
            const int row = rb + lrow;
            gload_lds16(Ap + (size_t)row * K + tt * BK + ((lchk ^ (row & 7)) * 8),
                        &As[buf][rb * 64]);
        }
    };
    auto stageB = [&](int buf, int tt, int half) {
        #pragma unroll
        for (int i = 0; i < 2; ++i) {
            const int s  = i * 8 + w;
            const int rb = ((s & 3) * 8) + ((s >> 2) * 64) + half * 32;
            const int row = rb + lrow;
            gload_lds16(Bp + (size_t)row * K + tt * BK + ((lchk ^ (row & 7)) * 8),
                        &Bs[buf][rb * 64]);
        }
    };
    auto readA = [&](int buf, int mh) {
        #pragma unroll
        for (int m = 0; m < 4; ++m)
            #pragma unroll
            for (int kk = 0; kk < 2; ++kk) {
                const int row = wr * 128 + mh * 64 + m * 16 + r16;
                af[m][kk] = *reinterpret_cast<const bf16x8*>(
                    &As[buf][row * 64 + (((kk * 4 + g4) ^ (row & 7)) * 8)]);
            }
    };
    auto readB = [&](int buf, int nh, bf16x8 (&br)[2][2]) {
        #pragma unroll
        for (int n = 0; n < 2; ++n)
            #pragma unroll
            for (int kk = 0; kk < 2; ++kk) {
                const int row = wc * 64 + nh * 32 + n * 16 + r16;
                br[n][kk] = *reinterpret_cast<const bf16x8*>(
                    &Bs[buf][row * 64 + (((kk * 4 + g4) ^ (row & 7)) * 8)]);
            }
    };
    auto mma = [&](bf16x8 (&br)[2][2], int mh, int nh) {
        __builtin_amdgcn_s_setprio(1);
        #pragma unroll
        for (int m = 0; m < 4; ++m)
            #pragma unroll
            for (int n = 0; n < 2; ++n)
                #pragma unroll
                for (int kk = 0; kk < 2; ++kk)
                    acc[mh * 4 + m][nh * 2 + n] = __builtin_amdgcn_mfma_f32_16x16x32_bf16(
                        af[m][kk], br[n][kk], acc[mh * 4 + m][nh * 2 + n], 0, 0, 0);
        __builtin_amdgcn_s_setprio(0);
    };

    stageA(0, 0, 0); stageB(0, 0, 0); stageB(0, 0, 1); stageA(0, 0, 1);
    WAITV(4);
    BAR();

    for (int t = 0; t < NT - 1; ++t) {
        const int buf = t & 1;
        readA(buf, 0); readB(buf, 0, b0);
        stageA(buf ^ 1, t + 1, 0); stageB(buf ^ 1, t + 1, 0);
        BAR();
        mma(b0, 0, 0);
        WAITV(6);
        BAR();
        readB(buf, 1, b1);
        stageB(buf ^ 1, t + 1, 1);
        BAR();
        mma(b1, 0, 1);
        WAITV(6);
        BAR();
        readA(buf, 1);
        stageA(buf ^ 1, t + 1, 1);
        BAR();
        mma(b1, 1, 1);
        BAR();
        mma(b0, 1, 0);
        WAITV(4);
        BAR();
    }
    {
        const int buf = (NT - 1) & 1;
        readA(buf, 0); readB(buf, 0, b0);
        BAR();
        mma(b0, 0, 0);
        WAITV(2);
        BAR();
        readB(buf, 1, b1);
        mma(b1, 0, 1);
        WAITV(0);
        readA(buf, 1);
        mma(b1, 1, 1);
        mma(b0, 1, 0);
    }

    const size_t crow0 = (size_t)bm * 256 + wr * 128;
    const size_t ccol0 = (size_t)bn * 256 + wc * 64;
    #pragma unroll
    for (int m = 0; m < 8; ++m)
        #pragma unroll
        for (int n = 0; n < 4; ++n)
            #pragma unroll
            for (int r = 0; r < 4; ++r) {
                const size_t row = crow0 + m * 16 + g4 * 4 + r;
                const size_t col = ccol0 + n * 16 + r16;
                if constexpr (sizeof(CT) == 2) C[row * ldc + col] = (CT)f2b(acc[m][n][r]);
                else                           C[row * ldc + col] = (CT)acc[m][n][r];
            }
}

// ---------------------------------------------------------------------------
// 3) RoPE in-place on q/k cols of qkv. Q part additionally scaled by 1/sqrt(HD).
// ---------------------------------------------------------------------------
__global__ __launch_bounds__(256) void rope_kernel(unsigned short* __restrict__ qkv,
                                                   const float* __restrict__ fc,
                                                   const float* __restrict__ fs) {
    constexpr float SCALE = 0.08838834764831845f;    // 1/sqrt(128)
    const int idx = blockIdx.x * 256 + threadIdx.x;   // 2048 rows * 640 groups
    const int s = idx / 640, g = idx - s * 640;
    const int col = g * 8;                            // within first 5120 cols
    unsigned short* p = qkv + (size_t)s * QKVW + col;
    u16x8 v = *reinterpret_cast<const u16x8*>(p);
    const int i0 = (col & 127) >> 1;
    f32x4 c  = *reinterpret_cast<const f32x4*>(fc + s * 64 + i0);
    f32x4 sn = *reinterpret_cast<const f32x4*>(fs + s * 64 + i0);
    const float post = (col < DD) ? SCALE : 1.0f;
    u16x8 o;
    #pragma unroll
    for (int j = 0; j < 4; ++j) {
        float e  = b2f(v[2*j]);
        float od = b2f(v[2*j+1]);
        o[2*j]   = f2b((e * c[j] - od * sn[j]) * post);
        o[2*j+1] = f2b((e * sn[j] + od * c[j]) * post);
    }
    *reinterpret_cast<u16x8*>(p) = o;
}

// ---------------------------------------------------------------------------
// 4) Transpose V part of qkv (cols 5120..6144) into Vt[kvh][128][S2]
// ---------------------------------------------------------------------------
__global__ __launch_bounds__(256) void transpose_v(const unsigned short* __restrict__ qkv,
                                                   unsigned short* __restrict__ Vt) {
    __shared__ unsigned short tile[64][72];
    const int d0g = blockIdx.x * 64;
    const int s0  = blockIdx.y * 64;
    const int kvh = d0g >> 7, dl0 = d0g & 127;
    const int tid = threadIdx.x;
    #pragma unroll
    for (int p = 0; p < 2; ++p) {
        const int sgi = p * 256 + tid;
        const int srow = sgi >> 3, dseg = sgi & 7;
        u16x8 v = *reinterpret_cast<const u16x8*>(
            qkv + (size_t)(s0 + srow) * QKVW + 5120 + d0g + dseg * 8);
        #pragma unroll
        for (int j = 0; j < 8; ++j) tile[srow][dseg * 8 + j] = v[j];
    }
    __syncthreads();
    #pragma unroll
    for (int p = 0; p < 2; ++p) {
        const int sgi = p * 256 + tid;
        const int drow = sgi >> 3, sseg = sgi & 7;
        u16x8 v;
        #pragma unroll
        for (int j = 0; j < 8; ++j) v[j] = tile[sseg * 8 + j][drow];
        *reinterpret_cast<u16x8*>(
            Vt + (size_t)kvh * HD2 * S2 + (size_t)(dl0 + drow) * S2 + s0 + sseg * 8) = v;
    }
}

// ---------------------------------------------------------------------------
// 5) Flash attention v3: 2048 independent 1-wave blocks (64 thr).
//    grid (8, 256): x = kvh (XCD-pinned), y = qidx*4 + head-in-group.
//    qw = (63-qidx)*32 -> longest chunks dispatched first.
//    K/V read per-lane straight from L2 (kvh's K+V = 1MB, L2-resident,
//    XCD-pinned). No block barriers, no staging. LDS = per-wave P tile only.
//    Occupancy: VGPR-limited ~8 waves/CU (2x round 3). T5 setprio on MFMA.
// ---------------------------------------------------------------------------
__global__ __launch_bounds__(64) void attn_kernel(const unsigned short* __restrict__ Qkv,
                                                  const unsigned short* __restrict__ Vt,
                                                  unsigned short* __restrict__ O) {
    __shared__ unsigned short Plds[32][72];      // pad 72: 2-way (free) on reads

    const int kvh  = blockIdx.x;                 // 0..7
    const int h    = kvh * 4 + (blockIdx.y & 3);
    const int qidx = blockIdx.y >> 2;            // 0..63
    const int qw   = (63 - qidx) * 32;           // wave's first q row (longest first)
    const int lane = threadIdx.x;
    const int r16 = lane & 15, g4 = lane >> 4;

    const unsigned short* Kbase = Qkv + DD + kvh * HD2;      // + kv*QKVW + d
    const unsigned short* Vtb   = Vt + (size_t)kvh * HD2 * S2;

    // Q fragments: rows qw + m*16 + r16, k-slices f*32 + g4*8 (pre-scaled in rope)
    bf16x8 qf[2][4];
    #pragma unroll
    for (int m = 0; m < 2; ++m)
        #pragma unroll
        for (int f = 0; f < 4; ++f)
            qf[m][f] = *reinterpret_cast<const bf16x8*>(
                Qkv + (size_t)(qw + m * 16 + r16) * QKVW + h * HD2 + f * 32 + g4 * 8);

    f32x4 o[2][8] = {};
    float mr[2][4], lr[2][4];
    #pragma unroll
    for (int m = 0; m < 2; ++m)
        #pragma unroll
        for (int r = 0; r < 4; ++r) { mr[m][r] = -3e38f; lr[m][r] = 0.f; }

    const int ntw = ((qw + 95) >> 6);            // tiles covering kv <= qw+31
    for (int t = 0; t < ntw; ++t) {
        const int kv0 = t * 64;

        // ---- QK^T: S[q 32][kv 64], A=Q rows, B=K rows (from L2) ----
        f32x4 sa[2][4] = {};
        #pragma unroll
        for (int kb = 0; kb < 4; ++kb) {
            bf16x8 kf[4];
            #pragma unroll
            for (int f = 0; f < 4; ++f)
                kf[f] = *reinterpret_cast<const bf16x8*>(
                    Kbase + (size_t)(kv0 + kb * 16 + r16) * QKVW + f * 32 + g4 * 8);
            __builtin_amdgcn_s_setprio(1);
            #pragma unroll
            for (int m = 0; m < 2; ++m)
                #pragma unroll
                for (int f = 0; f < 4; ++f)
                    sa[m][kb] = __builtin_amdgcn_mfma_f32_16x16x32_bf16(
                        qf[m][f], kf[f], sa[m][kb], 0, 0, 0);
            __builtin_amdgcn_s_setprio(0);
        }
        // ---- causal mask (logits pre-scaled via Q) ----
        const bool needmask = (kv0 + 63 > qw);
        float sv[2][4][4];
        #pragma unroll
        for (int m = 0; m < 2; ++m)
            #pragma unroll
            for (int kb = 0; kb < 4; ++kb)
                #pragma unroll
                for (int r = 0; r < 4; ++r) {
                    float xx = sa[m][kb][r];
                    if (needmask) {
                        const int kvg = kv0 + kb * 16 + r16;
                        const int qg  = qw + m * 16 + g4 * 4 + r;
                        xx = (kvg > qg) ? -3e38f : xx;
                    }
                    sv[m][kb][r] = xx;
                }
        // ---- row max (regs then 16-lane shfl tree) ----
        float rowm[2][4];
        #pragma unroll
        for (int m = 0; m < 2; ++m)
            #pragma unroll
            for (int r = 0; r < 4; ++r)
                rowm[m][r] = fmaxf(fmaxf(sv[m][0][r], sv[m][1][r]),
                                   fmaxf(sv[m][2][r], sv[m][3][r]));
        #pragma unroll
        for (int off = 1; off <= 8; off <<= 1)
            #pragma unroll
            for (int m = 0; m < 2; ++m)
                #pragma unroll
                for (int r = 0; r < 4; ++r)
                    rowm[m][r] = fmaxf(rowm[m][r], __shfl_xor(rowm[m][r], off));
        // ---- defer-max online softmax (T13, THR=8) ----
        float gmax = -3e38f;
        #pragma unroll
        for (int m = 0; m < 2; ++m)
            #pragma unroll
            for (int r = 0; r < 4; ++r)
                gmax = fmaxf(gmax, rowm[m][r] - mr[m][r]);
        if (!__all(gmax <= 8.0f)) {
            float corr[2][4];
            #pragma unroll
            for (int m = 0; m < 2; ++m)
                #pragma unroll
                for (int r = 0; r < 4; ++r) {
                    const float mn = fmaxf(mr[m][r], rowm[m][r]);
                    corr[m][r] = __expf(mr[m][r] - mn);
                    mr[m][r] = mn;
                    lr[m][r] *= corr[m][r];
                }
            #pragma unroll
            for (int m = 0; m < 2; ++m)
                #pragma unroll
                for (int n = 0; n < 8; ++n)
                    #pragma unroll
                    for (int r = 0; r < 4; ++r)
                        o[m][n][r] *= corr[m][r];
        }
        // ---- P = exp(S - m), row sums ----
        float rs[2][4] = {};
        #pragma unroll
        for (int m = 0; m < 2; ++m)
            #pragma unroll
            for (int kb = 0; kb < 4; ++kb)
                #pragma unroll
                for (int r = 0; r < 4; ++r) {
                    const float pp = __expf(sv[m][kb][r] - mr[m][r]);
                    sv[m][kb][r] = pp;
                    rs[m][r] += pp;
                }
        #pragma unroll
        for (int off = 1; off <= 8; off <<= 1)
            #pragma unroll
            for (int m = 0; m < 2; ++m)
                #pragma unroll
                for (int r = 0; r < 4; ++r)
                    rs[m][r] += __shfl_xor(rs[m][r], off);
        #pragma unroll
        for (int m = 0; m < 2; ++m)
            #pragma unroll
            for (int r = 0; r < 4; ++r)
                lr[m][r] += rs[m][r];
        // ---- P -> bf16 via per-wave LDS (D-layout write, A-frag read) ----
        #pragma unroll
        for (int m = 0; m < 2; ++m)
            #pragma unroll
            for (int kb = 0; kb < 4; ++kb)
                #pragma unroll
                for (int r = 0; r < 4; ++r)
                    Plds[m * 16 + g4 * 4 + r][kb * 16 + r16] = f2b(sv[m][kb][r]);
        asm volatile("s_waitcnt lgkmcnt(0)" ::: "memory");
        bf16x8 pa[2][2];
        #pragma unroll
        for (int m = 0; m < 2; ++m)
            #pragma unroll
            for (int kvs = 0; kvs < 2; ++kvs)
                pa[m][kvs] = *reinterpret_cast<const bf16x8*>(
                    &Plds[m * 16 + r16][kvs * 32 + g4 * 8]);
        // ---- PV: O[q][d] += P[q][kv] * Vt[d][kv]  (V from L2) ----
        #pragma unroll
        for (int kvs = 0; kvs < 2; ++kvs)
            #pragma unroll
            for (int n = 0; n < 8; ++n) {
                const bf16x8 vb = *reinterpret_cast<const bf16x8*>(
                    Vtb + (size_t)(n * 16 + r16) * S2 + kv0 + kvs * 32 + g4 * 8);
                __builtin_amdgcn_s_setprio(1);
                #pragma unroll
                for (int m = 0; m < 2; ++m)
                    o[m][n] = __builtin_amdgcn_mfma_f32_16x16x32_bf16(
                        pa[m][kvs], vb, o[m][n], 0, 0, 0);
                __builtin_amdgcn_s_setprio(0);
            }
    }

    // ---- normalize + write (bf16, (s, h*128+d)) ----
    float inv[2][4];
    #pragma unroll
    for (int m = 0; m < 2; ++m)
        #pragma unroll
        for (int r = 0; r < 4; ++r) inv[m][r] = 1.0f / lr[m][r];
    #pragma unroll
    for (int m = 0; m < 2; ++m)
        #pragma unroll
        for (int n = 0; n < 8; ++n)
            #pragma unroll
            for (int r = 0; r < 4; ++r)
                O[(size_t)(qw + m * 16 + g4 * 4 + r) * DD + h * HD2 + n * 16 + r16] =
                    f2b(o[m][n][r] * inv[m][r]);
}

// ---------------------------------------------------------------------------
extern "C" void kernel_launch(void* const* d_in, const int* in_sizes, int n_in,
                              void* d_out, int out_size, void* d_ws, size_t ws_size,
                              hipStream_t stream) {
    (void)in_sizes; (void)n_in; (void)out_size; (void)ws_size;
    const float* x  = (const float*)d_in[0];
    const float* wq = (const float*)d_in[1];
    const float* wk = (const float*)d_in[2];
    const float* wv = (const float*)d_in[3];
    const float* wo = (const float*)d_in[4];
    // d_in[5] = mask (causal tril; computed analytically in-kernel)
    const float* fc = (const float*)d_in[6];
    const float* fs = (const float*)d_in[7];
    float* out = (float*)d_out;

    unsigned short* ws = (unsigned short*)d_ws;
    const size_t M1 = 1024 * 1024;
    unsigned short* xb  = ws;              // 8M  (x bf16)
    unsigned short* wqb = ws + 8  * M1;    // 16M
    unsigned short* wkb = ws + 24 * M1;    // 4M
    unsigned short* wvb = ws + 28 * M1;    // 4M
    unsigned short* wob = ws + 32 * M1;    // 16M
    unsigned short* qkv = ws + 48 * M1;    // 12M (S x 6144)
    unsigned short* vt  = ws + 60 * M1;    // 2M  (KVH x 128 x S)
    unsigned short* ob  = ws + 62 * M1;    // 8M  (S x 4096)

    cvt_all<<<2048, 256, 0, stream>>>(x, wq, wk, wv, wo, ws);
    gemm256<unsigned short><<<dim3(24, 8), 512, 0, stream>>>(
        xb, wqb, wkb, wvb, 4096, 5120, qkv, QKVW);
    rope_kernel<<<5120, 256, 0, stream>>>(qkv, fc, fs);
    transpose_v<<<dim3(16, 32), 256, 0, stream>>>(qkv, vt);
    attn_kernel<<<dim3(8, 256), 64, 0, stream>>>(qkv, vt, ob);
    gemm256<float><<<dim3(16, 8), 512, 0, stream>>>(
        ob, wob, wob, wob, 1 << 30, 1 << 30, out, DD);
}

// Round 5
// 362.518 us; speedup vs baseline: 1.3571x; 1.3571x over previous
//
#include <hip/hip_runtime.h>
#include <hip/hip_bf16.h>
#include <stdint.h>

// Problem constants
#define S2   2048
#define DD   4096
#define NH   32
#define NKVH 8
#define HD2  128
// qkv buffer row width: 4096 (q) + 1024 (k) + 1024 (v)
#define QKVW 6144

typedef __bf16 bf16x8 __attribute__((ext_vector_type(8)));
typedef float  f32x4  __attribute__((ext_vector_type(4)));
typedef unsigned short u16x8 __attribute__((ext_vector_type(8)));
typedef unsigned short u16x4 __attribute__((ext_vector_type(4)));

__device__ __forceinline__ unsigned short f2b(float f) {
    unsigned int u = __builtin_bit_cast(unsigned int, f);
    unsigned int r = (u + 0x7FFFu + ((u >> 16) & 1u)) >> 16;   // RNE
    return (unsigned short)r;
}
__device__ __forceinline__ float b2f(unsigned short h) {
    unsigned int u = ((unsigned int)h) << 16;
    return __builtin_bit_cast(float, u);
}
__device__ __forceinline__ unsigned cvt_pk_bf16(float a, float b) {
    unsigned r;
    asm("v_cvt_pk_bf16_f32 %0, %1, %2" : "=v"(r) : "v"(a), "v"(b));
    return r;   // lo16 = bf16(a), hi16 = bf16(b)
}

// global -> LDS direct copy, 16B per lane. LDS dest is wave-uniform base + lane*16.
__device__ __forceinline__ void gload_lds16(const void* g, void* lds) {
    __builtin_amdgcn_global_load_lds(
        (const __attribute__((address_space(1))) void*)(uintptr_t)g,
        (__attribute__((address_space(3))) void*)(uint32_t)(uintptr_t)lds,
        16, 0, 0);
}

// raw barrier (no vmcnt drain) + compiler memory fences so LDS ops don't cross
#define BAR() do { asm volatile("" ::: "memory"); \
                   __builtin_amdgcn_s_barrier();  \
                   asm volatile("" ::: "memory"); } while (0)
#define WAITV(n) asm volatile("s_waitcnt vmcnt(" #n ")" ::: "memory")

// ---------------------------------------------------------------------------
// 1) fp32 -> bf16 conversion for x, wq, wk, wv, wo (concatenated into ws)
// ---------------------------------------------------------------------------
__global__ void cvt_all(const float* __restrict__ x,  const float* __restrict__ wq,
                        const float* __restrict__ wk, const float* __restrict__ wv,
                        const float* __restrict__ wo, unsigned short* __restrict__ dst) {
    const long long NG = 12LL * 1024 * 1024;  // float4 groups
    const long long stride = (long long)gridDim.x * blockDim.x;
    for (long long g = (long long)blockIdx.x * blockDim.x + threadIdx.x; g < NG; g += stride) {
        const float* src; long long off;
        if      (g < 2LL*1024*1024) { src = x;  off = g; }
        else if (g < 6LL*1024*1024) { src = wq; off = g - 2LL*1024*1024; }
        else if (g < 7LL*1024*1024) { src = wk; off = g - 6LL*1024*1024; }
        else if (g < 8LL*1024*1024) { src = wv; off = g - 7LL*1024*1024; }
        else                        { src = wo; off = g - 8LL*1024*1024; }
        f32x4 v = *reinterpret_cast<const f32x4*>(src + off * 4);
        u16x4 o;
        o[0] = f2b(v[0]); o[1] = f2b(v[1]); o[2] = f2b(v[2]); o[3] = f2b(v[3]);
        *reinterpret_cast<u16x4*>(dst + g * 4) = o;
    }
}

// ---------------------------------------------------------------------------
// 2) GEMM  C[M x N] = A[M x K] * B^T, 256x256 tile, BK=64, 8-phase schedule
//    (T2 st-swizzle + T3/T4 counted vmcnt + T5 setprio). Unchanged from r3.
// ---------------------------------------------------------------------------
template<typename CT>
__global__ __launch_bounds__(512) void gemm256(
    const unsigned short* __restrict__ A,
    const unsigned short* __restrict__ B0,
    const unsigned short* __restrict__ B1,
    const unsigned short* __restrict__ B2,
    int nb0, int nb01,
    CT* __restrict__ C, int ldc)
{
    constexpr int K = 4096, BK = 64, NT = K / BK;
    __shared__ unsigned short As[2][256 * 64];
    __shared__ unsigned short Bs[2][256 * 64];

    const int bm = blockIdx.y, bn = blockIdx.x;
    const int tid = threadIdx.x;
    const int w = tid >> 6, lane = tid & 63;
    const int wr = w >> 2, wc = w & 3;          // 2M x 4N wave grid
    const int r16 = lane & 15, g4 = lane >> 4;

    const int bn0 = bn * 256;
    const unsigned short* Bp;
    if      (bn0 < nb0)  Bp = B0 + (size_t)bn0 * K;
    else if (bn0 < nb01) Bp = B1 + (size_t)(bn0 - nb0) * K;
    else                 Bp = B2 + (size_t)(bn0 - nb01) * K;
    const unsigned short* Ap = A + (size_t)bm * 256 * K;

    const int lrow = lane >> 3;   // 0..7
    const int lchk = lane & 7;    // 0..7

    f32x4 acc[8][4] = {};
    bf16x8 af[4][2], b0[2][2], b1[2][2];

    auto stageA = [&](int buf, int tt, int half) {
        #pragma unroll
        for (int i = 0; i < 2; ++i) {
            const int s  = i * 8 + w;                                  // 0..15
            const int rb = ((s & 7) * 8) + ((s >> 3) * 128) + half * 64;
            const int row = rb + lrow;
            gload_lds16(Ap + (size_t)row * K + tt * BK + ((lchk ^ (row & 7)) * 8),
                        &As[buf][rb * 64]);
        }
    };
    auto stageB = [&](int buf, int tt, int half) {
        #pragma unroll
        for (int i = 0; i < 2; ++i) {
            const int s  = i * 8 + w;
            const int rb = ((s & 3) * 8) + ((s >> 2) * 64) + half * 32;
            const int row = rb + lrow;
            gload_lds16(Bp + (size_t)row * K + tt * BK + ((lchk ^ (row & 7)) * 8),
                        &Bs[buf][rb * 64]);
        }
    };
    auto readA = [&](int buf, int mh) {
        #pragma unroll
        for (int m = 0; m < 4; ++m)
            #pragma unroll
            for (int kk = 0; kk < 2; ++kk) {
                const int row = wr * 128 + mh * 64 + m * 16 + r16;
                af[m][kk] = *reinterpret_cast<const bf16x8*>(
                    &As[buf][row * 64 + (((kk * 4 + g4) ^ (row & 7)) * 8)]);
            }
    };
    auto readB = [&](int buf, int nh, bf16x8 (&br)[2][2]) {
        #pragma unroll
        for (int n = 0; n < 2; ++n)
            #pragma unroll
            for (int kk = 0; kk < 2; ++kk) {
                const int row = wc * 64 + nh * 32 + n * 16 + r16;
                br[n][kk] = *reinterpret_cast<const bf16x8*>(
                    &Bs[buf][row * 64 + (((kk * 4 + g4) ^ (row & 7)) * 8)]);
            }
    };
    auto mma = [&](bf16x8 (&br)[2][2], int mh, int nh) {
        __builtin_amdgcn_s_setprio(1);
        #pragma unroll
        for (int m = 0; m < 4; ++m)
            #pragma unroll
            for (int n = 0; n < 2; ++n)
                #pragma unroll
                for (int kk = 0; kk < 2; ++kk)
                    acc[mh * 4 + m][nh * 2 + n] = __builtin_amdgcn_mfma_f32_16x16x32_bf16(
                        af[m][kk], br[n][kk], acc[mh * 4 + m][nh * 2 + n], 0, 0, 0);
        __builtin_amdgcn_s_setprio(0);
    };

    stageA(0, 0, 0); stageB(0, 0, 0); stageB(0, 0, 1); stageA(0, 0, 1);
    WAITV(4);
    BAR();

    for (int t = 0; t < NT - 1; ++t) {
        const int buf = t & 1;
        readA(buf, 0); readB(buf, 0, b0);
        stageA(buf ^ 1, t + 1, 0); stageB(buf ^ 1, t + 1, 0);
        BAR();
        mma(b0, 0, 0);
        WAITV(6);
        BAR();
        readB(buf, 1, b1);
        stageB(buf ^ 1, t + 1, 1);
        BAR();
        mma(b1, 0, 1);
        WAITV(6);
        BAR();
        readA(buf, 1);
        stageA(buf ^ 1, t + 1, 1);
        BAR();
        mma(b1, 1, 1);
        BAR();
        mma(b0, 1, 0);
        WAITV(4);
        BAR();
    }
    {
        const int buf = (NT - 1) & 1;
        readA(buf, 0); readB(buf, 0, b0);
        BAR();
        mma(b0, 0, 0);
        WAITV(2);
        BAR();
        readB(buf, 1, b1);
        mma(b1, 0, 1);
        WAITV(0);
        readA(buf, 1);
        mma(b1, 1, 1);
        mma(b0, 1, 0);
    }

    const size_t crow0 = (size_t)bm * 256 + wr * 128;
    const size_t ccol0 = (size_t)bn * 256 + wc * 64;
    #pragma unroll
    for (int m = 0; m < 8; ++m)
        #pragma unroll
        for (int n = 0; n < 4; ++n)
            #pragma unroll
            for (int r = 0; r < 4; ++r) {
                const size_t row = crow0 + m * 16 + g4 * 4 + r;
                const size_t col = ccol0 + n * 16 + r16;
                if constexpr (sizeof(CT) == 2) C[row * ldc + col] = (CT)f2b(acc[m][n][r]);
                else                           C[row * ldc + col] = (CT)acc[m][n][r];
            }
}

// ---------------------------------------------------------------------------
// 3) RoPE in-place on q/k cols of qkv. Q part scaled by log2(e)/sqrt(HD)
//    (folds attention logit scale AND the exp->exp2 conversion into Q).
// ---------------------------------------------------------------------------
__global__ __launch_bounds__(256) void rope_kernel(unsigned short* __restrict__ qkv,
                                                   const float* __restrict__ fc,
                                                   const float* __restrict__ fs) {
    constexpr float QSCALE = 0.08838834764831845f * 1.4426950408889634f; // 1/sqrt(128)*log2(e)
    const int idx = blockIdx.x * 256 + threadIdx.x;   // 2048 rows * 640 groups
    const int s = idx / 640, g = idx - s * 640;
    const int col = g * 8;                            // within first 5120 cols
    unsigned short* p = qkv + (size_t)s * QKVW + col;
    u16x8 v = *reinterpret_cast<const u16x8*>(p);
    const int i0 = (col & 127) >> 1;
    f32x4 c  = *reinterpret_cast<const f32x4*>(fc + s * 64 + i0);
    f32x4 sn = *reinterpret_cast<const f32x4*>(fs + s * 64 + i0);
    const float post = (col < DD) ? QSCALE : 1.0f;
    u16x8 o;
    #pragma unroll
    for (int j = 0; j < 4; ++j) {
        float e  = b2f(v[2*j]);
        float od = b2f(v[2*j+1]);
        o[2*j]   = f2b((e * c[j] - od * sn[j]) * post);
        o[2*j+1] = f2b((e * sn[j] + od * c[j]) * post);
    }
    *reinterpret_cast<u16x8*>(p) = o;
}

// ---------------------------------------------------------------------------
// 4) Transpose V part of qkv (cols 5120..6144) into Vt[kvh][128][S2]
// ---------------------------------------------------------------------------
__global__ __launch_bounds__(256) void transpose_v(const unsigned short* __restrict__ qkv,
                                                   unsigned short* __restrict__ Vt) {
    __shared__ unsigned short tile[64][72];
    const int d0g = blockIdx.x * 64;
    const int s0  = blockIdx.y * 64;
    const int kvh = d0g >> 7, dl0 = d0g & 127;
    const int tid = threadIdx.x;
    #pragma unroll
    for (int p = 0; p < 2; ++p) {
        const int sgi = p * 256 + tid;
        const int srow = sgi >> 3, dseg = sgi & 7;
        u16x8 v = *reinterpret_cast<const u16x8*>(
            qkv + (size_t)(s0 + srow) * QKVW + 5120 + d0g + dseg * 8);
        #pragma unroll
        for (int j = 0; j < 8; ++j) tile[srow][dseg * 8 + j] = v[j];
    }
    __syncthreads();
    #pragma unroll
    for (int p = 0; p < 2; ++p) {
        const int sgi = p * 256 + tid;
        const int drow = sgi >> 3, sseg = sgi & 7;
        u16x8 v;
        #pragma unroll
        for (int j = 0; j < 8; ++j) v[j] = tile[sseg * 8 + j][drow];
        *reinterpret_cast<u16x8*>(
            Vt + (size_t)kvh * HD2 * S2 + (size_t)(dl0 + drow) * S2 + s0 + sseg * 8) = v;
    }
}

// ---------------------------------------------------------------------------
// 5) Flash attention v5: r3's staged 4-wave structure + 2 blocks/CU + T12.
//    Grid (8, 64): x = kvh (XCD-pinned), y = chunk-desc*4 + head-in-group.
//    Each block: ONE 128-row chunk, 4 waves x 32 q-rows; 512 blocks = 2/CU
//    (LDS exactly 80KB), greedy scheduler pairs long+short chunks.
//    Swapped QK^T (A=K, B=Q) -> C[kv][q]: lane owns one q-row, 16 lane-local
//    kv values -> in-register max/sum + 2 shfl levels; P packed with
//    v_cvt_pk_bf16_f32 into fragment-ordered Plds (8 ds_write_b64,
//    conflict-free lane*16 ds_read_b128). Softmax in base-2 (exp2).
// ---------------------------------------------------------------------------
__global__ __launch_bounds__(256) void attn_kernel(const unsigned short* __restrict__ Qkv,
                                                   const unsigned short* __restrict__ Vt,
                                                   unsigned short* __restrict__ O) {
    __shared__ unsigned short Klds[2][64 * 128];   // 32 KB
    __shared__ unsigned short Vlds[2][128 * 64];   // 32 KB
    __shared__ unsigned short Plds[4][2048];       // 16 KB (4 KB/wave, frag-ordered)

    const int kvh = blockIdx.x;                  // 0..7
    const int h   = kvh * 4 + (blockIdx.y & 3);
    const int c   = 15 - (blockIdx.y >> 2);      // chunk, longest dispatched first
    const int w = threadIdx.x >> 6, lane = threadIdx.x & 63;
    const int r16 = lane & 15, g4 = lane >> 4;

    const int qw  = c * 128 + w * 32;            // wave's first q row
    const int ntB = 2 * c + 2;                   // 64-kv tiles this block iterates

    const unsigned short* Kbase = Qkv + DD + kvh * HD2;      // + kv*QKVW + d
    const unsigned short* Vtb   = Vt + (size_t)kvh * HD2 * S2;
    char* pw = (char*)(&Plds[w][0]);             // wave's 4KB P region

    // staging lane constants
    const int krow_l = lane >> 4;      // row within 4-row segment
    const int kchunk = lane & 15;      // 16B chunk within 256B K row
    const int vd_l   = lane >> 3;      // d within 8-row segment
    const int vchunk = lane & 7;       // 16B chunk within 128B V row

    // Q fragments (B-frag of swapped QK^T): rows qw+m*16+r16, d-slices f*32+g4*8
    bf16x8 qf[2][4];
    #pragma unroll
    for (int m = 0; m < 2; ++m)
        #pragma unroll
        for (int f = 0; f < 4; ++f)
            qf[m][f] = *reinterpret_cast<const bf16x8*>(
                Qkv + (size_t)(qw + m * 16 + r16) * QKVW + h * HD2 + f * 32 + g4 * 8);

    f32x4 o[2][8] = {};
    float mr[2] = {-3e38f, -3e38f};   // running max (log2 units) for q = m*16+r16
    float lr[2] = {0.f, 0.f};

    auto stage = [&](int buf, int kv0) {
        #pragma unroll
        for (int i = 0; i < 4; ++i) {
            const int seg = i * 4 + w;                     // 0..15
            const int row = seg * 4 + krow_l;              // kv row 0..63
            gload_lds16(Kbase + (size_t)(kv0 + row) * QKVW + ((kchunk ^ (row & 7)) * 8),
                        &Klds[buf][seg * 512]);
        }
        #pragma unroll
        for (int i = 0; i < 4; ++i) {
            const int seg = i * 4 + w;
            const int d = seg * 8 + vd_l;                  // d row 0..127
            gload_lds16(Vtb + (size_t)d * S2 + kv0 + ((vchunk ^ (d & 7)) * 8),
                        &Vlds[buf][seg * 512]);
        }
    };

    stage(0, 0);
    WAITV(0);
    __syncthreads();

    for (int t = 0; t < ntB; ++t) {
        const int buf = t & 1;
        const int kv0 = t * 64;
        if (t + 1 < ntB) stage(buf ^ 1, (t + 1) * 64);

        if (kv0 <= qw + 31) {                 // causal: this wave needs the tile
            // ---- QK^T swapped: sa[m][kb] = K_tile * Q^T -> C[kv][q] ----
            f32x4 sa[2][4] = {};
            #pragma unroll
            for (int kb = 0; kb < 4; ++kb) {
                bf16x8 kf[4];
                #pragma unroll
                for (int f = 0; f < 4; ++f)
                    kf[f] = *reinterpret_cast<const bf16x8*>(
                        &Klds[buf][(kb * 16 + r16) * 128 + (((f * 4 + g4) ^ (r16 & 7)) * 8)]);
                __builtin_amdgcn_s_setprio(1);
                #pragma unroll
                for (int m = 0; m < 2; ++m)
                    #pragma unroll
                    for (int f = 0; f < 4; ++f)
                        sa[m][kb] = __builtin_amdgcn_mfma_f32_16x16x32_bf16(
                            kf[f], qf[m][f], sa[m][kb], 0, 0, 0);
                __builtin_amdgcn_s_setprio(0);
            }
            // ---- causal mask: lane holds q = qw+m*16+r16, kv = kv0+kb*16+g4*4+r ----
            const bool needmask = (kv0 + 63 > qw);
            float sv[2][4][4];
            #pragma unroll
            for (int m = 0; m < 2; ++m)
                #pragma unroll
                for (int kb = 0; kb < 4; ++kb)
                    #pragma unroll
                    for (int r = 0; r < 4; ++r) {
                        float xx = sa[m][kb][r];
                        if (needmask) {
                            const int kvg = kv0 + kb * 16 + g4 * 4 + r;
                            const int qg  = qw + m * 16 + r16;
                            xx = (kvg > qg) ? -3e38f : xx;
                        }
                        sv[m][kb][r] = xx;
                    }
            // ---- per-q max: 15 in-lane ops + 2 shfl levels ----
            float rowm[2];
            #pragma unroll
            for (int m = 0; m < 2; ++m) {
                float a0 = fmaxf(fmaxf(sv[m][0][0], sv[m][0][1]), fmaxf(sv[m][0][2], sv[m][0][3]));
                float a1 = fmaxf(fmaxf(sv[m][1][0], sv[m][1][1]), fmaxf(sv[m][1][2], sv[m][1][3]));
                float a2 = fmaxf(fmaxf(sv[m][2][0], sv[m][2][1]), fmaxf(sv[m][2][2], sv[m][2][3]));
                float a3 = fmaxf(fmaxf(sv[m][3][0], sv[m][3][1]), fmaxf(sv[m][3][2], sv[m][3][3]));
                rowm[m] = fmaxf(fmaxf(a0, a1), fmaxf(a2, a3));
            }
            #pragma unroll
            for (int m = 0; m < 2; ++m) {
                rowm[m] = fmaxf(rowm[m], __shfl_xor(rowm[m], 16));
                rowm[m] = fmaxf(rowm[m], __shfl_xor(rowm[m], 32));
            }
            // ---- defer-max (T13, base-2 THR = 11.5 ~ e^8) ----
            const float gmax = fmaxf(rowm[0] - mr[0], rowm[1] - mr[1]);
            if (!__all(gmax <= 11.5f)) {
                float corr[2];
                #pragma unroll
                for (int m = 0; m < 2; ++m) {
                    const float mn = fmaxf(mr[m], rowm[m]);
                    corr[m] = exp2f(mr[m] - mn);
                    mr[m] = mn;
                    lr[m] *= corr[m];
                }
                #pragma unroll
                for (int m = 0; m < 2; ++m)
                    #pragma unroll
                    for (int r = 0; r < 4; ++r) {
                        const float co = __shfl(corr[m], (lane & 48) | (g4 * 4 + r));
                        #pragma unroll
                        for (int n = 0; n < 8; ++n) o[m][n][r] *= co;
                    }
            }
            // ---- P = exp2(S - m), row sums (in-lane + 2 shfl) ----
            float rs[2] = {0.f, 0.f};
            #pragma unroll
            for (int m = 0; m < 2; ++m)
                #pragma unroll
                for (int kb = 0; kb < 4; ++kb)
                    #pragma unroll
                    for (int r = 0; r < 4; ++r) {
                        const float pp = exp2f(sv[m][kb][r] - mr[m]);
                        sv[m][kb][r] = pp;
                        rs[m] += pp;
                    }
            #pragma unroll
            for (int m = 0; m < 2; ++m) {
                rs[m] += __shfl_xor(rs[m], 16);
                rs[m] += __shfl_xor(rs[m], 32);
                lr[m] += rs[m];
            }
            // ---- pack P pairs (cvt_pk) -> fragment-ordered Plds, 8 b64 writes ----
            #pragma unroll
            for (int m = 0; m < 2; ++m)
                #pragma unroll
                for (int kb = 0; kb < 4; ++kb) {
                    const unsigned w0 = cvt_pk_bf16(sv[m][kb][0], sv[m][kb][1]);
                    const unsigned w1 = cvt_pk_bf16(sv[m][kb][2], sv[m][kb][3]);
                    int wa = m * 2048 + ((kb * 2) + (g4 >> 1)) * 256 + r16 * 16 + (g4 & 1) * 8;
                    wa ^= (r16 >> 3) << 4;
                    *reinterpret_cast<unsigned long long*>(pw + wa) =
                        (unsigned long long)w0 | ((unsigned long long)w1 << 32);
                }
            asm volatile("s_waitcnt lgkmcnt(0)" ::: "memory");
            bf16x8 pa[2][2];
            #pragma unroll
            for (int m = 0; m < 2; ++m)
                #pragma unroll
                for (int kvs = 0; kvs < 2; ++kvs) {
                    int ra = m * 2048 + kvs * 1024 + lane * 16;
                    ra ^= (r16 >> 3) << 4;
                    pa[m][kvs] = *reinterpret_cast<const bf16x8*>(pw + ra);
                }
            // ---- PV: O[q][d] += P[q][kv] * Vt[d][kv] ----
            #pragma unroll
            for (int kvs = 0; kvs < 2; ++kvs)
                #pragma unroll
                for (int n = 0; n < 8; ++n) {
                    const bf16x8 vb = *reinterpret_cast<const bf16x8*>(
                        &Vlds[buf][(n * 16 + r16) * 64 + (((kvs * 4 + g4) ^ (r16 & 7)) * 8)]);
                    __builtin_amdgcn_s_setprio(1);
                    #pragma unroll
                    for (int m = 0; m < 2; ++m)
                        o[m][n] = __builtin_amdgcn_mfma_f32_16x16x32_bf16(
                            pa[m][kvs], vb, o[m][n], 0, 0, 0);
                    __builtin_amdgcn_s_setprio(0);
                }
        }

        WAITV(0);
        __syncthreads();
    }

    // ---- normalize (broadcast 1/lr to o-layout lanes) + write ----
    float inv[2];
    #pragma unroll
    for (int m = 0; m < 2; ++m) inv[m] = 1.0f / lr[m];
    #pragma unroll
    for (int m = 0; m < 2; ++m)
        #pragma unroll
        for (int r = 0; r < 4; ++r) {
            const float iv = __shfl(inv[m], (lane & 48) | (g4 * 4 + r));
            #pragma unroll
            for (int n = 0; n < 8; ++n)
                O[(size_t)(qw + m * 16 + g4 * 4 + r) * DD + h * HD2 + n * 16 + r16] =
                    f2b(o[m][n][r] * iv);
        }
}

// ---------------------------------------------------------------------------
extern "C" void kernel_launch(void* const* d_in, const int* in_sizes, int n_in,
                              void* d_out, int out_size, void* d_ws, size_t ws_size,
                              hipStream_t stream) {
    (void)in_sizes; (void)n_in; (void)out_size; (void)ws_size;
    const float* x  = (const float*)d_in[0];
    const float* wq = (const float*)d_in[1];
    const float* wk = (const float*)d_in[2];
    const float* wv = (const float*)d_in[3];
    const float* wo = (const float*)d_in[4];
    // d_in[5] = mask (causal tril; computed analytically in-kernel)
    const float* fc = (const float*)d_in[6];
    const float* fs = (const float*)d_in[7];
    float* out = (float*)d_out;

    unsigned short* ws = (unsigned short*)d_ws;
    const size_t M1 = 1024 * 1024;
    unsigned short* xb  = ws;              // 8M  (x bf16)
    unsigned short* wqb = ws + 8  * M1;    // 16M
    unsigned short* wkb = ws + 24 * M1;    // 4M
    unsigned short* wvb = ws + 28 * M1;    // 4M
    unsigned short* wob = ws + 32 * M1;    // 16M
    unsigned short* qkv = ws + 48 * M1;    // 12M (S x 6144)
    unsigned short* vt  = ws + 60 * M1;    // 2M  (KVH x 128 x S)
    unsigned short* ob  = ws + 62 * M1;    // 8M  (S x 4096)

    cvt_all<<<2048, 256, 0, stream>>>(x, wq, wk, wv, wo, ws);
    gemm256<unsigned short><<<dim3(24, 8), 512, 0, stream>>>(
        xb, wqb, wkb, wvb, 4096, 5120, qkv, QKVW);
    rope_kernel<<<5120, 256, 0, stream>>>(qkv, fc, fs);
    transpose_v<<<dim3(16, 32), 256, 0, stream>>>(qkv, vt);
    attn_kernel<<<dim3(8, 64), 256, 0, stream>>>(qkv, vt, ob);
    gemm256<float><<<dim3(16, 8), 512, 0, stream>>>(
        ob, wob, wob, wob, 1 << 30, 1 << 30, out, DD);
}

// Round 6
// 342.876 us; speedup vs baseline: 1.4348x; 1.0573x over previous
//
#include <hip/hip_runtime.h>
#include <hip/hip_bf16.h>
#include <stdint.h>

// Problem constants
#define S2   2048
#define DD   4096
#define NH   32
#define NKVH 8
#define HD2  128
// qkv buffer row width: 4096 (q) + 1024 (k) + 1024 (v)
#define QKVW 6144

typedef __bf16 bf16x8 __attribute__((ext_vector_type(8)));
typedef float  f32x4  __attribute__((ext_vector_type(4)));
typedef unsigned short u16x8 __attribute__((ext_vector_type(8)));
typedef unsigned short u16x4 __attribute__((ext_vector_type(4)));

__device__ __forceinline__ unsigned short f2b(float f) {
    unsigned int u = __builtin_bit_cast(unsigned int, f);
    unsigned int r = (u + 0x7FFFu + ((u >> 16) & 1u)) >> 16;   // RNE
    return (unsigned short)r;
}
__device__ __forceinline__ float b2f(unsigned short h) {
    unsigned int u = ((unsigned int)h) << 16;
    return __builtin_bit_cast(float, u);
}
__device__ __forceinline__ unsigned cvt_pk_bf16(float a, float b) {
    unsigned r;
    asm("v_cvt_pk_bf16_f32 %0, %1, %2" : "=v"(r) : "v"(a), "v"(b));
    return r;   // lo16 = bf16(a), hi16 = bf16(b)
}

// global -> LDS direct copy, 16B per lane. LDS dest is wave-uniform base + lane*16.
__device__ __forceinline__ void gload_lds16(const void* g, void* lds) {
    __builtin_amdgcn_global_load_lds(
        (const __attribute__((address_space(1))) void*)(uintptr_t)g,
        (__attribute__((address_space(3))) void*)(uint32_t)(uintptr_t)lds,
        16, 0, 0);
}

// raw barrier (no vmcnt drain) + compiler memory fences so LDS ops don't cross
#define BAR() do { asm volatile("" ::: "memory"); \
                   __builtin_amdgcn_s_barrier();  \
                   asm volatile("" ::: "memory"); } while (0)
#define WAITV(n) asm volatile("s_waitcnt vmcnt(" #n ")" ::: "memory")
#define LGKM0()  asm volatile("s_waitcnt lgkmcnt(0)" ::: "memory")

// ---------------------------------------------------------------------------
// 1) fp32 -> bf16 conversion for x, wq, wk, wv, wo (concatenated into ws)
// ---------------------------------------------------------------------------
__global__ void cvt_all(const float* __restrict__ x,  const float* __restrict__ wq,
                        const float* __restrict__ wk, const float* __restrict__ wv,
                        const float* __restrict__ wo, unsigned short* __restrict__ dst) {
    const long long NG = 12LL * 1024 * 1024;  // float4 groups
    const long long stride = (long long)gridDim.x * blockDim.x;
    for (long long g = (long long)blockIdx.x * blockDim.x + threadIdx.x; g < NG; g += stride) {
        const float* src; long long off;
        if      (g < 2LL*1024*1024) { src = x;  off = g; }
        else if (g < 6LL*1024*1024) { src = wq; off = g - 2LL*1024*1024; }
        else if (g < 7LL*1024*1024) { src = wk; off = g - 6LL*1024*1024; }
        else if (g < 8LL*1024*1024) { src = wv; off = g - 7LL*1024*1024; }
        else                        { src = wo; off = g - 8LL*1024*1024; }
        f32x4 v = *reinterpret_cast<const f32x4*>(src + off * 4);
        u16x4 o;
        o[0] = f2b(v[0]); o[1] = f2b(v[1]); o[2] = f2b(v[2]); o[3] = f2b(v[3]);
        *reinterpret_cast<u16x4*>(dst + g * 4) = o;
    }
}

// ---------------------------------------------------------------------------
// 2) GEMM  C[2048 x N] = A[2048 x 4096] * B^T, ring-4 deep-prefetch schedule.
//    BM=256, BK=32, 4-slot LDS ring, prefetch distance 3 tiles (~1500 cyc >
//    HBM latency). Per wave: 128x64 output (acc f32x4[8][4]); 2 phases/tile,
//    16 MFMA each. NW=8 (BN=256, QKV) or NW=4 (BN=128, O-proj, 256 blocks).
//    vmcnt ledger (loads/tile/wave L = 16/NW + BN/16/NW):
//      end of tile t: WAITV(2L) -> tile t+1 fully landed (tails L, 0).
//    lgkmcnt(0) before each barrier seals LDS reads before ring overwrite
//    (stage into slot (t+3)&3 == (t-1)&3 issues only after t-1's end-barrier).
//    T2 64B-row XOR swizzle: LDS slot c holds global chunk c^(row&3).
//    XCD pinning: bm = lin&7 (A-tile L2-resident per XCD).
// ---------------------------------------------------------------------------
template<int BN, int NW, typename CT>
__global__ __launch_bounds__(NW * 64) void gemm_rk(
    const unsigned short* __restrict__ A,
    const unsigned short* __restrict__ B0,
    const unsigned short* __restrict__ B1,
    const unsigned short* __restrict__ B2,
    int nb0, int nb01,
    CT* __restrict__ C, int ldc)
{
    constexpr int K = 4096, BK = 32, NT = K / BK;      // 128 K-tiles
    constexpr int AUN = 16;                            // 256 rows / 16
    constexpr int BUN = BN / 16;
    constexpr int AL = AUN / NW;                       // A stage loads/wave
    constexpr int BL = BUN / NW;                       // B stage loads/wave
    __shared__ unsigned short As[4][256 * BK];
    __shared__ unsigned short Bs[4][BN * BK];

    const int lin = blockIdx.y * gridDim.x + blockIdx.x;
    const int bm = lin & 7;                            // XCD-pinned M-tile
    const int bn = lin >> 3;
    const int tid = threadIdx.x;
    const int w = tid >> 6, lane = tid & 63;
    const int wr = (NW == 8) ? (w >> 2) : (w >> 1);    // 2 M-halves of 128
    const int wc = (NW == 8) ? (w & 3) : (w & 1);      // BN/64 N-quads
    const int r16 = lane & 15, g4 = lane >> 4;

    const int bn0 = bn * BN;
    const unsigned short* Bp;
    if      (bn0 < nb0)  Bp = B0 + (size_t)bn0 * K;
    else if (bn0 < nb01) Bp = B1 + (size_t)(bn0 - nb0) * K;
    else                 Bp = B2 + (size_t)(bn0 - nb01) * K;
    const unsigned short* Ap = A + (size_t)bm * 256 * K;

    // staging lane mapping: within a 16-row unit, lane covers row=lane>>2,
    // 16B chunk slot lane&3; source chunk pre-swizzled (slot^(row&3)).
    const int srow = lane >> 2;
    const int schk = lane & 3;

    f32x4 acc[8][4] = {};
    bf16x8 af[8], bf0[2], bf1[2];

    auto stageA = [&](int buf, int tt) {
        #pragma unroll
        for (int i = 0; i < AL; ++i) {
            const int u = i * NW + w;                  // 0..15
            const int row = u * 16 + srow;
            gload_lds16(Ap + (size_t)row * K + tt * BK + ((schk ^ (row & 3)) * 8),
                        &As[buf][u * 512]);
        }
    };
    auto stageB = [&](int buf, int tt) {
        #pragma unroll
        for (int i = 0; i < BL; ++i) {
            const int u = i * NW + w;                  // 0..BUN-1
            const int row = u * 16 + srow;
            gload_lds16(Bp + (size_t)row * K + tt * BK + ((schk ^ (row & 3)) * 8),
                        &Bs[buf][u * 512]);
        }
    };
    auto readA = [&](int buf) {
        #pragma unroll
        for (int m = 0; m < 8; ++m) {
            const int row = wr * 128 + m * 16 + r16;
            af[m] = *reinterpret_cast<const bf16x8*>(
                &As[buf][row * BK + ((g4 ^ (row & 3)) * 8)]);
        }
    };
    auto readB = [&](int buf, int nh, bf16x8 (&br)[2]) {
        #pragma unroll
        for (int n = 0; n < 2; ++n) {
            const int row = wc * 64 + nh * 32 + n * 16 + r16;
            br[n] = *reinterpret_cast<const bf16x8*>(
                &Bs[buf][row * BK + ((g4 ^ (row & 3)) * 8)]);
        }
    };
    auto mma = [&](bf16x8 (&br)[2], int nh) {
        __builtin_amdgcn_s_setprio(1);
        #pragma unroll
        for (int m = 0; m < 8; ++m)
            #pragma unroll
            for (int n = 0; n < 2; ++n)
                acc[m][nh * 2 + n] = __builtin_amdgcn_mfma_f32_16x16x32_bf16(
                    af[m], br[n], acc[m][nh * 2 + n], 0, 0, 0);
        __builtin_amdgcn_s_setprio(0);
    };

    // prologue: stage tiles 0,1,2 (issue order A0 B0 A1 B1 A2 B2)
    stageA(0, 0); stageB(0, 0);
    stageA(1, 1); stageB(1, 1);
    stageA(2, 2); stageB(2, 2);
    // wait tile 0 (newer: A1,B1,A2,B2 = 2*(AL+BL) loads), all waves
    if constexpr (NW == 8) WAITV(8); else WAITV(12);
    BAR();

    #pragma unroll 4
    for (int t = 0; t < NT; ++t) {
        const int buf = t & 3;
        // ---- phase 0: n-half 0 ----
        readA(buf);
        readB(buf, 0, bf0);
        if (t + 3 < NT) stageA((t + 3) & 3, t + 3);
        mma(bf0, 0);
        LGKM0();
        BAR();
        // ---- phase 1: n-half 1 ----
        readB(buf, 1, bf1);
        if (t + 3 < NT) stageB((t + 3) & 3, t + 3);
        mma(bf1, 1);
        LGKM0();
        // gate tile t+1 landed (per-wave), then barrier (cross-wave)
        if (t < NT - 3)       { if constexpr (NW == 8) WAITV(8); else WAITV(12); }
        else if (t == NT - 3) { if constexpr (NW == 8) WAITV(4); else WAITV(6); }
        else if (t == NT - 2) { WAITV(0); }
        BAR();
    }

    // ---- epilogue: C write ----
    const size_t crow0 = (size_t)bm * 256 + wr * 128;
    const size_t ccol0 = (size_t)bn * BN + wc * 64;
    #pragma unroll
    for (int m = 0; m < 8; ++m)
        #pragma unroll
        for (int n = 0; n < 4; ++n)
            #pragma unroll
            for (int r = 0; r < 4; ++r) {
                const size_t row = crow0 + m * 16 + g4 * 4 + r;
                const size_t col = ccol0 + n * 16 + r16;
                if constexpr (sizeof(CT) == 2) C[row * ldc + col] = (CT)f2b(acc[m][n][r]);
                else                           C[row * ldc + col] = (CT)acc[m][n][r];
            }
}

// ---------------------------------------------------------------------------
// 3) RoPE in-place on q/k cols of qkv. Q part scaled by log2(e)/sqrt(HD)
//    (folds attention logit scale AND the exp->exp2 conversion into Q).
// ---------------------------------------------------------------------------
__global__ __launch_bounds__(256) void rope_kernel(unsigned short* __restrict__ qkv,
                                                   const float* __restrict__ fc,
                                                   const float* __restrict__ fs) {
    constexpr float QSCALE = 0.08838834764831845f * 1.4426950408889634f; // 1/sqrt(128)*log2(e)
    const int idx = blockIdx.x * 256 + threadIdx.x;   // 2048 rows * 640 groups
    const int s = idx / 640, g = idx - s * 640;
    const int col = g * 8;                            // within first 5120 cols
    unsigned short* p = qkv + (size_t)s * QKVW + col;
    u16x8 v = *reinterpret_cast<const u16x8*>(p);
    const int i0 = (col & 127) >> 1;
    f32x4 c  = *reinterpret_cast<const f32x4*>(fc + s * 64 + i0);
    f32x4 sn = *reinterpret_cast<const f32x4*>(fs + s * 64 + i0);
    const float post = (col < DD) ? QSCALE : 1.0f;
    u16x8 o;
    #pragma unroll
    for (int j = 0; j < 4; ++j) {
        float e  = b2f(v[2*j]);
        float od = b2f(v[2*j+1]);
        o[2*j]   = f2b((e * c[j] - od * sn[j]) * post);
        o[2*j+1] = f2b((e * sn[j] + od * c[j]) * post);
    }
    *reinterpret_cast<u16x8*>(p) = o;
}

// ---------------------------------------------------------------------------
// 4) Transpose V part of qkv (cols 5120..6144) into Vt[kvh][128][S2]
// ---------------------------------------------------------------------------
__global__ __launch_bounds__(256) void transpose_v(const unsigned short* __restrict__ qkv,
                                                   unsigned short* __restrict__ Vt) {
    __shared__ unsigned short tile[64][72];
    const int d0g = blockIdx.x * 64;
    const int s0  = blockIdx.y * 64;
    const int kvh = d0g >> 7, dl0 = d0g & 127;
    const int tid = threadIdx.x;
    #pragma unroll
    for (int p = 0; p < 2; ++p) {
        const int sgi = p * 256 + tid;
        const int srow = sgi >> 3, dseg = sgi & 7;
        u16x8 v = *reinterpret_cast<const u16x8*>(
            qkv + (size_t)(s0 + srow) * QKVW + 5120 + d0g + dseg * 8);
        #pragma unroll
        for (int j = 0; j < 8; ++j) tile[srow][dseg * 8 + j] = v[j];
    }
    __syncthreads();
    #pragma unroll
    for (int p = 0; p < 2; ++p) {
        const int sgi = p * 256 + tid;
        const int drow = sgi >> 3, sseg = sgi & 7;
        u16x8 v;
        #pragma unroll
        for (int j = 0; j < 8; ++j) v[j] = tile[sseg * 8 + j][drow];
        *reinterpret_cast<u16x8*>(
            Vt + (size_t)kvh * HD2 * S2 + (size_t)(dl0 + drow) * S2 + s0 + sseg * 8) = v;
    }
}

// ---------------------------------------------------------------------------
// 5) Flash attention (unchanged from round 5).
// ---------------------------------------------------------------------------
__global__ __launch_bounds__(256) void attn_kernel(const unsigned short* __restrict__ Qkv,
                                                   const unsigned short* __restrict__ Vt,
                                                   unsigned short* __restrict__ O) {
    __shared__ unsigned short Klds[2][64 * 128];   // 32 KB
    __shared__ unsigned short Vlds[2][128 * 64];   // 32 KB
    __shared__ unsigned short Plds[4][2048];       // 16 KB (4 KB/wave, frag-ordered)

    const int kvh = blockIdx.x;                  // 0..7
    const int h   = kvh * 4 + (blockIdx.y & 3);
    const int c   = 15 - (blockIdx.y >> 2);      // chunk, longest dispatched first
    const int w = threadIdx.x >> 6, lane = threadIdx.x & 63;
    const int r16 = lane & 15, g4 = lane >> 4;

    const int qw  = c * 128 + w * 32;            // wave's first q row
    const int ntB = 2 * c + 2;                   // 64-kv tiles this block iterates

    const unsigned short* Kbase = Qkv + DD + kvh * HD2;      // + kv*QKVW + d
    const unsigned short* Vtb   = Vt + (size_t)kvh * HD2 * S2;
    char* pw = (char*)(&Plds[w][0]);             // wave's 4KB P region

    // staging lane constants
    const int krow_l = lane >> 4;      // row within 4-row segment
    const int kchunk = lane & 15;      // 16B chunk within 256B K row
    const int vd_l   = lane >> 3;      // d within 8-row segment
    const int vchunk = lane & 7;       // 16B chunk within 128B V row

    // Q fragments (B-frag of swapped QK^T): rows qw+m*16+r16, d-slices f*32+g4*8
    bf16x8 qf[2][4];
    #pragma unroll
    for (int m = 0; m < 2; ++m)
        #pragma unroll
        for (int f = 0; f < 4; ++f)
            qf[m][f] = *reinterpret_cast<const bf16x8*>(
                Qkv + (size_t)(qw + m * 16 + r16) * QKVW + h * HD2 + f * 32 + g4 * 8);

    f32x4 o[2][8] = {};
    float mr[2] = {-3e38f, -3e38f};   // running max (log2 units) for q = m*16+r16
    float lr[2] = {0.f, 0.f};

    auto stage = [&](int buf, int kv0) {
        #pragma unroll
        for (int i = 0; i < 4; ++i) {
            const int seg = i * 4 + w;                     // 0..15
            const int row = seg * 4 + krow_l;              // kv row 0..63
            gload_lds16(Kbase + (size_t)(kv0 + row) * QKVW + ((kchunk ^ (row & 7)) * 8),
                        &Klds[buf][seg * 512]);
        }
        #pragma unroll
        for (int i = 0; i < 4; ++i) {
            const int seg = i * 4 + w;
            const int d = seg * 8 + vd_l;                  // d row 0..127
            gload_lds16(Vtb + (size_t)d * S2 + kv0 + ((vchunk ^ (d & 7)) * 8),
                        &Vlds[buf][seg * 512]);
        }
    };

    stage(0, 0);
    WAITV(0);
    __syncthreads();

    for (int t = 0; t < ntB; ++t) {
        const int buf = t & 1;
        const int kv0 = t * 64;
        if (t + 1 < ntB) stage(buf ^ 1, (t + 1) * 64);

        if (kv0 <= qw + 31) {                 // causal: this wave needs the tile
            // ---- QK^T swapped: sa[m][kb] = K_tile * Q^T -> C[kv][q] ----
            f32x4 sa[2][4] = {};
            #pragma unroll
            for (int kb = 0; kb < 4; ++kb) {
                bf16x8 kf[4];
                #pragma unroll
                for (int f = 0; f < 4; ++f)
                    kf[f] = *reinterpret_cast<const bf16x8*>(
                        &Klds[buf][(kb * 16 + r16) * 128 + (((f * 4 + g4) ^ (r16 & 7)) * 8)]);
                __builtin_amdgcn_s_setprio(1);
                #pragma unroll
                for (int m = 0; m < 2; ++m)
                    #pragma unroll
                    for (int f = 0; f < 4; ++f)
                        sa[m][kb] = __builtin_amdgcn_mfma_f32_16x16x32_bf16(
                            kf[f], qf[m][f], sa[m][kb], 0, 0, 0);
                __builtin_amdgcn_s_setprio(0);
            }
            // ---- causal mask: lane holds q = qw+m*16+r16, kv = kv0+kb*16+g4*4+r ----
            const bool needmask = (kv0 + 63 > qw);
            float sv[2][4][4];
            #pragma unroll
            for (int m = 0; m < 2; ++m)
                #pragma unroll
                for (int kb = 0; kb < 4; ++kb)
                    #pragma unroll
                    for (int r = 0; r < 4; ++r) {
                        float xx = sa[m][kb][r];
                        if (needmask) {
                            const int kvg = kv0 + kb * 16 + g4 * 4 + r;
                            const int qg  = qw + m * 16 + r16;
                            xx = (kvg > qg) ? -3e38f : xx;
                        }
                        sv[m][kb][r] = xx;
                    }
            // ---- per-q max: 15 in-lane ops + 2 shfl levels ----
            float rowm[2];
            #pragma unroll
            for (int m = 0; m < 2; ++m) {
                float a0 = fmaxf(fmaxf(sv[m][0][0], sv[m][0][1]), fmaxf(sv[m][0][2], sv[m][0][3]));
                float a1 = fmaxf(fmaxf(sv[m][1][0], sv[m][1][1]), fmaxf(sv[m][1][2], sv[m][1][3]));
                float a2 = fmaxf(fmaxf(sv[m][2][0], sv[m][2][1]), fmaxf(sv[m][2][2], sv[m][2][3]));
                float a3 = fmaxf(fmaxf(sv[m][3][0], sv[m][3][1]), fmaxf(sv[m][3][2], sv[m][3][3]));
                rowm[m] = fmaxf(fmaxf(a0, a1), fmaxf(a2, a3));
            }
            #pragma unroll
            for (int m = 0; m < 2; ++m) {
                rowm[m] = fmaxf(rowm[m], __shfl_xor(rowm[m], 16));
                rowm[m] = fmaxf(rowm[m], __shfl_xor(rowm[m], 32));
            }
            // ---- defer-max (T13, base-2 THR = 11.5 ~ e^8) ----
            const float gmax = fmaxf(rowm[0] - mr[0], rowm[1] - mr[1]);
            if (!__all(gmax <= 11.5f)) {
                float corr[2];
                #pragma unroll
                for (int m = 0; m < 2; ++m) {
                    const float mn = fmaxf(mr[m], rowm[m]);
                    corr[m] = exp2f(mr[m] - mn);
                    mr[m] = mn;
                    lr[m] *= corr[m];
                }
                #pragma unroll
                for (int m = 0; m < 2; ++m)
                    #pragma unroll
                    for (int r = 0; r < 4; ++r) {
                        const float co = __shfl(corr[m], (lane & 48) | (g4 * 4 + r));
                        #pragma unroll
                        for (int n = 0; n < 8; ++n) o[m][n][r] *= co;
                    }
            }
            // ---- P = exp2(S - m), row sums (in-lane + 2 shfl) ----
            float rs[2] = {0.f, 0.f};
            #pragma unroll
            for (int m = 0; m < 2; ++m)
                #pragma unroll
                for (int kb = 0; kb < 4; ++kb)
                    #pragma unroll
                    for (int r = 0; r < 4; ++r) {
                        const float pp = exp2f(sv[m][kb][r] - mr[m]);
                        sv[m][kb][r] = pp;
                        rs[m] += pp;
                    }
            #pragma unroll
            for (int m = 0; m < 2; ++m) {
                rs[m] += __shfl_xor(rs[m], 16);
                rs[m] += __shfl_xor(rs[m], 32);
                lr[m] += rs[m];
            }
            // ---- pack P pairs (cvt_pk) -> fragment-ordered Plds, 8 b64 writes ----
            #pragma unroll
            for (int m = 0; m < 2; ++m)
                #pragma unroll
                for (int kb = 0; kb < 4; ++kb) {
                    const unsigned w0 = cvt_pk_bf16(sv[m][kb][0], sv[m][kb][1]);
                    const unsigned w1 = cvt_pk_bf16(sv[m][kb][2], sv[m][kb][3]);
                    int wa = m * 2048 + ((kb * 2) + (g4 >> 1)) * 256 + r16 * 16 + (g4 & 1) * 8;
                    wa ^= (r16 >> 3) << 4;
                    *reinterpret_cast<unsigned long long*>(pw + wa) =
                        (unsigned long long)w0 | ((unsigned long long)w1 << 32);
                }
            asm volatile("s_waitcnt lgkmcnt(0)" ::: "memory");
            bf16x8 pa[2][2];
            #pragma unroll
            for (int m = 0; m < 2; ++m)
                #pragma unroll
                for (int kvs = 0; kvs < 2; ++kvs) {
                    int ra = m * 2048 + kvs * 1024 + lane * 16;
                    ra ^= (r16 >> 3) << 4;
                    pa[m][kvs] = *reinterpret_cast<const bf16x8*>(pw + ra);
                }
            // ---- PV: O[q][d] += P[q][kv] * Vt[d][kv] ----
            #pragma unroll
            for (int kvs = 0; kvs < 2; ++kvs)
                #pragma unroll
                for (int n = 0; n < 8; ++n) {
                    const bf16x8 vb = *reinterpret_cast<const bf16x8*>(
                        &Vlds[buf][(n * 16 + r16) * 64 + (((kvs * 4 + g4) ^ (r16 & 7)) * 8)]);
                    __builtin_amdgcn_s_setprio(1);
                    #pragma unroll
                    for (int m = 0; m < 2; ++m)
                        o[m][n] = __builtin_amdgcn_mfma_f32_16x16x32_bf16(
                            pa[m][kvs], vb, o[m][n], 0, 0, 0);
                    __builtin_amdgcn_s_setprio(0);
                }
        }

        WAITV(0);
        __syncthreads();
    }

    // ---- normalize (broadcast 1/lr to o-layout lanes) + write ----
    float inv[2];
    #pragma unroll
    for (int m = 0; m < 2; ++m) inv[m] = 1.0f / lr[m];
    #pragma unroll
    for (int m = 0; m < 2; ++m)
        #pragma unroll
        for (int r = 0; r < 4; ++r) {
            const float iv = __shfl(inv[m], (lane & 48) | (g4 * 4 + r));
            #pragma unroll
            for (int n = 0; n < 8; ++n)
                O[(size_t)(qw + m * 16 + g4 * 4 + r) * DD + h * HD2 + n * 16 + r16] =
                    f2b(o[m][n][r] * iv);
        }
}

// ---------------------------------------------------------------------------
extern "C" void kernel_launch(void* const* d_in, const int* in_sizes, int n_in,
                              void* d_out, int out_size, void* d_ws, size_t ws_size,
                              hipStream_t stream) {
    (void)in_sizes; (void)n_in; (void)out_size; (void)ws_size;
    const float* x  = (const float*)d_in[0];
    const float* wq = (const float*)d_in[1];
    const float* wk = (const float*)d_in[2];
    const float* wv = (const float*)d_in[3];
    const float* wo = (const float*)d_in[4];
    // d_in[5] = mask (causal tril; computed analytically in-kernel)
    const float* fc = (const float*)d_in[6];
    const float* fs = (const float*)d_in[7];
    float* out = (float*)d_out;

    unsigned short* ws = (unsigned short*)d_ws;
    const size_t M1 = 1024 * 1024;
    unsigned short* xb  = ws;              // 8M  (x bf16)
    unsigned short* wqb = ws + 8  * M1;    // 16M
    unsigned short* wkb = ws + 24 * M1;    // 4M
    unsigned short* wvb = ws + 28 * M1;    // 4M
    unsigned short* wob = ws + 32 * M1;    // 16M
    unsigned short* qkv = ws + 48 * M1;    // 12M (S x 6144)
    unsigned short* vt  = ws + 60 * M1;    // 2M  (KVH x 128 x S)
    unsigned short* ob  = ws + 62 * M1;    // 8M  (S x 4096)

    cvt_all<<<2048, 256, 0, stream>>>(x, wq, wk, wv, wo, ws);
    gemm_rk<256, 8, unsigned short><<<dim3(24, 8), 512, 0, stream>>>(
        xb, wqb, wkb, wvb, 4096, 5120, qkv, QKVW);
    rope_kernel<<<5120, 256, 0, stream>>>(qkv, fc, fs);
    transpose_v<<<dim3(16, 32), 256, 0, stream>>>(qkv, vt);
    attn_kernel<<<dim3(8, 64), 256, 0, stream>>>(qkv, vt, ob);
    gemm_rk<128, 4, float><<<dim3(32, 8), 256, 0, stream>>>(
        ob, wob, wob, wob, 1 << 30, 1 << 30, out, DD);
}